// Round 6
// baseline (332.163 us; speedup 1.0000x reference)
//
#include <hip/hip_runtime.h>
#include <hip/hip_fp16.h>

typedef _Float16 f16;
typedef _Float16 f16x8 __attribute__((ext_vector_type(8)));
typedef float f32x4 __attribute__((ext_vector_type(4)));
typedef unsigned long long ull;

#define BB 4
#define TT 16
#define HH 64
#define WW 64
#define CC 32
#define FF 64
#define GG 256  // 4F gates

__device__ __forceinline__ float hsig(float z) {
    return fminf(fmaxf(0.2f * z + 0.5f, 0.f), 1.f);
}
__device__ __forceinline__ float tanh_fast(float x) {
    return 1.f - 2.f / (__expf(2.f * x) + 1.f);
}

__device__ __forceinline__ void async_copy16(const void* g, void* l) {
    __builtin_amdgcn_global_load_lds(
        (const __attribute__((address_space(1))) unsigned*)g,
        (__attribute__((address_space(3))) unsigned*)l, 16, 0, 0);
}

// --- Weight prep: writes TWO layouts.
// Layout A (fused, per-quarter): wcatA[q][p][j][slot][e], q=f-quarter, p=phase(9),
//   j=piece(12, 8 K-rows each), slot = n ^ ((j&3)<<1) (bank-decorrelating XOR, n = cls*16+fidx),
//   e=elem(8). One phase-unit = 64 slots x 16B = 1024B (one global_load_lds per piece).
// Layout B (fallback, round-4 piece-major): wcatB[p][j][gate][e].
__global__ void wprep_kernel(const float* __restrict__ wx, const float* __restrict__ wh,
                             f16* __restrict__ wcatA, f16* __restrict__ wcatB) {
    int e0 = blockIdx.x * 256 + threadIdx.x;   // grid covers exactly 221184
    float val; int k, ng;
    if (e0 < 9 * CC * GG) {                    // Wx: e = (tap*32+c)*256 + n
        ng = e0 & 255; k = e0 >> 8; val = wx[e0];
    } else {                                   // Wh: e = (tap*64+f)*256 + n
        int e = e0 - 9 * CC * GG;
        ng = e & 255; k = 288 + (e >> 8); val = wh[e];
    }
    int p = k / 96, r = k % 96, j = r >> 3, el = r & 7;
    wcatB[((p * 12 + j) * 256 + ng) * 8 + el] = (f16)val;
    int q = (ng >> 4) & 3;                     // f-channel quarter
    int n = ((ng >> 6) << 4) | (ng & 15);      // cls*16 + fidx-in-quarter
    int slot = n ^ ((j & 3) << 1);
    wcatA[(((q * 9 + p) * 12 + j) * 64 + slot) * 8 + el] = (f16)val;
}

// x staging with fused LayerNorm: one thread per patch pixel (324 threads)
__device__ __forceinline__ void stage_x_ln(const float* __restrict__ x, int bb, int t,
                                           int tY, int tX, int tid,
                                           const float* sg, const float* sb,
                                           f16* xpatch) {
    if (tid < 324) {
        int py = tid / 18, pxx = tid - py * 18;
        int gy = tY * 16 - 1 + py, gx = tX * 16 - 1 + pxx;
        if (gy >= 0 && gy < HH && gx >= 0 && gx < WW) {
            const float* xp = x + ((size_t)(bb * TT + t) * (HH * WW) + gy * WW + gx) * CC;
            float v[CC];
            float s = 0.f, s2 = 0.f;
#pragma unroll
            for (int c = 0; c < CC; c += 4) {
                float4 t4 = *(const float4*)(xp + c);
                v[c] = t4.x; v[c + 1] = t4.y; v[c + 2] = t4.z; v[c + 3] = t4.w;
                s += t4.x + t4.y + t4.z + t4.w;
                s2 += t4.x * t4.x + t4.y * t4.y + t4.z * t4.z + t4.w * t4.w;
            }
            float mu = s * (1.f / CC);
            float var = s2 * (1.f / CC) - mu * mu;
            float rs = rsqrtf(var + 1e-3f);
            f16 o[CC];
#pragma unroll
            for (int c = 0; c < CC; c++)
                o[c] = (f16)((v[c] - mu) * rs * sg[c] + sb[c]);
            *(f16x8*)&xpatch[tid * 40]      = *(f16x8*)&o[0];
            *(f16x8*)&xpatch[tid * 40 + 8]  = *(f16x8*)&o[8];
            *(f16x8*)&xpatch[tid * 40 + 16] = *(f16x8*)&o[16];
            *(f16x8*)&xpatch[tid * 40 + 24] = *(f16x8*)&o[24];
        }
    }
}

// ======== Fused: 16 ConvLSTM steps; 64 tiles(16x16 px) x 4 f-quarters = 256 blocks ========
// 1 block/CU, 512 threads (8 waves), LDS ~97 KB. Each block computes 16 f-channels for its
// 256 px; weights/CU/step = 110.6 KB (4x less than full-gate split). h exchanged through
// the coherent point via relaxed agent atomics (proven r3/r4 protocol); per-task producer
// flags (tile-quarter granularity) replace barriers. LN staged one step ahead in phase 4
// (xpatch only read in phases 0-2); pool from the staged h patch (one-step shifted).
// XOR slot swizzle -> conflict-free B ds_reads.
__global__ __launch_bounds__(512, 2)
void fused_kernel(const float* __restrict__ x, const float* __restrict__ gamma,
                  const float* __restrict__ beta, const f16* __restrict__ wcatA,
                  const float* __restrict__ bs, f16* __restrict__ halo,
                  float* __restrict__ out, unsigned* __restrict__ flags) {
    __shared__ __align__(16) f16 xpatch[324 * 40];   // 18x18 px, 32ch + 8 pad   (25.9 KB)
    __shared__ __align__(16) f16 hpatch[324 * 72];   // 18x18 px, 64ch + 8 pad   (46.7 KB)
    __shared__ __align__(16) f16 wbuf[2 * 6144];     // 2 x 12 pieces x 1024 B   (24.6 KB)
    __shared__ float sg[CC], sb[CC];

    int tid = threadIdx.x;
    int bid = blockIdx.x;
    int Q = bid & 3, tl = bid >> 2;            // quarter, tile
    int bb = tl >> 4, tY = (tl >> 2) & 3, tX = tl & 3;
    int lane = tid & 63, w = tid >> 6;         // wave in [0,8)
    int quad = lane >> 4, noff = lane & 15;

    if (tid < CC) sg[tid] = gamma[tid];
    else if (tid < 2 * CC) sb[tid - CC] = beta[tid - CC];

    {   // zero patches once: OOB borders stay zero forever; h[0] = 0
        f16x8 z8 = {0, 0, 0, 0, 0, 0, 0, 0};
        for (int i = tid; i < 1620; i += 512) ((f16x8*)xpatch)[i] = z8;
        for (int i = tid; i < 2916; i += 512) ((f16x8*)hpatch)[i] = z8;
    }

    // global weight pointers: wave w loads piece w (and 8+w for w<4) of each phase
    const char* gw0 = (const char*)wcatA + (size_t)Q * 110592 + w * 1024 + lane * 16;
    const char* gw1 = gw0 + 8192;

    int fch = (Q << 4) + noff;                 // global f-channel
    float b_i = bs[fch], b_f = bs[64 + fch], b_c = bs[128 + fch], b_o = bs[192 + fch];

    float creg[2][4];
#pragma unroll
    for (int mt = 0; mt < 2; mt++)
#pragma unroll
        for (int r = 0; r < 4; r++) creg[mt][r] = 0.f;

    // A-read bases: pixel row = w*2+mt, col = noff (A-frag m-row = noff)
    int arow[2], hrow[2];
#pragma unroll
    for (int mt = 0; mt < 2; mt++) {
        arow[mt] = ((w * 2 + mt) * 18 + noff) * 40 + (quad << 3);
        hrow[mt] = ((w * 2 + mt) * 18 + noff) * 72 + (quad << 3);
    }
    // B-read base: piece j=cw*4+quad at j*512; slot = (cls*16+noff)^(quad<<1)
    int qB = quad * 512 + ((noff ^ (quad << 1)) << 3);

    __syncthreads();  // zero-init + sg/sb visible

    // initial prefetch: phase 0 -> buffer half 0; stage x[0]
    async_copy16(gw0, &wbuf[w * 512]);
    if (w < 4) async_copy16(gw1, &wbuf[4096 + w * 512]);
    stage_x_ln(x, bb, 0, tY, tX, tid, sg, sb, xpatch);

    for (int t = 0; t < TT; t++) {
        f16* wrd0 = &wbuf[(t & 1) * 6144];
        f16* wrd1 = &wbuf[((t + 1) & 1) * 6144];

        f32x4 acc[2][4];
#pragma unroll
        for (int i = 0; i < 2; i++)
#pragma unroll
            for (int j = 0; j < 4; j++) acc[i][j] = (f32x4){0.f, 0.f, 0.f, 0.f};

        // ---- 9 phases (0-2: x taps; 3-8: h taps), fully unrolled ----
#pragma unroll
        for (int p = 0; p < 9; ++p) {
            __syncthreads();  // vmcnt drain: read-buffer ready, prior reads of write-buffer done
            {
                int nc = (p == 8) ? 0 : p + 1;    // p=8 prefetches next step's phase 0
                f16* wdst = (p & 1) ? wrd0 : wrd1;
                async_copy16(gw0 + nc * 12288, &wdst[w * 512]);
                if (w < 4) async_copy16(gw1 + nc * 12288, &wdst[4096 + w * 512]);
            }
            const f16* wbp = (p & 1) ? wrd1 : wrd0;
#pragma unroll
            for (int cw = 0; cw < 3; ++cw) {
                int c = p * 3 + cw;               // compile-time K-chunk id
                bool isx = c < 9;
                int hc = c - 9;
                int tap = isx ? c : (hc >> 1);
                int coff = isx ? 0 : ((hc & 1) << 5);
                int dy = tap / 3, dx = tap % 3;
                f16x8 a[2];
#pragma unroll
                for (int mt = 0; mt < 2; mt++)
                    a[mt] = isx
                        ? *(const f16x8*)&xpatch[arow[mt] + (dy * 18 + dx) * 40]
                        : *(const f16x8*)&hpatch[hrow[mt] + (dy * 18 + dx) * 72 + coff];
#pragma unroll
                for (int cls = 0; cls < 4; cls++) {
                    f16x8 bf = *(const f16x8*)&wbp[qB + cw * 2048 + cls * 128];
                    acc[0][cls] = __builtin_amdgcn_mfma_f32_16x16x32_f16(a[0], bf, acc[0][cls], 0, 0, 0);
                    acc[1][cls] = __builtin_amdgcn_mfma_f32_16x16x32_f16(a[1], bf, acc[1][cls], 0, 0, 0);
                }
            }
            // ---- h staging in phase 2 (h first consumed at phase 3) ----
            if (p == 2 && t > 0) {
#pragma unroll
                for (int k2 = 0; k2 < 3; k2++) {
                    int tau = tid + k2 * 512;
                    if (tau < 1296) {             // 324 px x 4 ch-groups of 16 (32B each)
                        int pxi = tau >> 2, grp = tau & 3;
                        int py = pxi / 18, pxx = pxi - py * 18;
                        int gy = tY * 16 - 1 + py, gx = tX * 16 - 1 + pxx;
                        if (gy >= 0 && gy < HH && gx >= 0 && gx < WW) {
                            int nb = ((bb * 16 + (gy >> 4) * 4 + (gx >> 4)) << 2) | grp;
                            while (__hip_atomic_load(&flags[nb], __ATOMIC_RELAXED,
                                                     __HIP_MEMORY_SCOPE_AGENT) < (unsigned)t)
                                __builtin_amdgcn_s_sleep(1);
                            const ull* src = (const ull*)(halo
                                + ((size_t)(t * BB + bb) * (HH * WW) + gy * WW + gx) * FF
                                + grp * 16);
                            ull v0 = __hip_atomic_load(src, __ATOMIC_RELAXED,
                                                       __HIP_MEMORY_SCOPE_AGENT);
                            ull v1 = __hip_atomic_load(src + 1, __ATOMIC_RELAXED,
                                                       __HIP_MEMORY_SCOPE_AGENT);
                            ull v2 = __hip_atomic_load(src + 2, __ATOMIC_RELAXED,
                                                       __HIP_MEMORY_SCOPE_AGENT);
                            ull v3 = __hip_atomic_load(src + 3, __ATOMIC_RELAXED,
                                                       __HIP_MEMORY_SCOPE_AGENT);
                            ull* dst = (ull*)&hpatch[pxi * 72 + grp * 16];
                            dst[0] = v0; dst[1] = v1; dst[2] = v2; dst[3] = v3;
                        }
                    }
                }
            }
            // ---- pool h[t] from the staged patch (interior) -> out slot t-1 ----
            if (p == 3 && t > 0) {
                int a_ = tid >> 6, b_ = (tid >> 3) & 7, ch = (tid & 7) << 3;
                const f16* h00 = &hpatch[((1 + 2 * a_) * 18 + 1 + 2 * b_) * 72 + ch];
                f16x8 q00 = *(const f16x8*)h00;
                f16x8 q01 = *(const f16x8*)(h00 + 72);
                f16x8 q10 = *(const f16x8*)(h00 + 18 * 72);
                f16x8 q11 = *(const f16x8*)(h00 + 18 * 72 + 72);
                float o8[8];
#pragma unroll
                for (int j = 0; j < 8; j++)
                    o8[j] = fmaxf(fmaxf((float)q00[j], (float)q01[j]),
                                  fmaxf((float)q10[j], (float)q11[j]));
                size_t ofs = ((((size_t)bb * TT + (t - 1)) * 32 + tY * 8 + a_) * 32
                              + (tX * 8 + b_)) * 64 + ch;
                *(float4*)(out + ofs) = *(float4*)&o8[0];
                *(float4*)(out + ofs + 4) = *(float4*)&o8[4];
            }
            // ---- stage x[t+1] in phase 4 (xpatch only read in phases 0-2) ----
            if (p == 4 && t + 1 < TT)
                stage_x_ln(x, bb, t + 1, tY, tX, tid, sg, sb, xpatch);
        }

        // ---- epilogue: gates + state; h -> global (write-through, agent-coherent) ----
#pragma unroll
        for (int mt = 0; mt < 2; mt++) {
#pragma unroll
            for (int r = 0; r < 4; r++) {
                // C/D: pixel row = w*2+mt, col = quad*4+r; gate col = noff
                int gy = tY * 16 + w * 2 + mt, gx = tX * 16 + (quad << 2) + r;
                float zi = acc[mt][0][r] + b_i;
                float zf = acc[mt][1][r] + b_f;
                float zc = acc[mt][2][r] + b_c;
                float zo = acc[mt][3][r] + b_o;
                float ig = hsig(zi), fg = hsig(zf), og = hsig(zo);
                float cn = fg * creg[mt][r] + ig * tanh_fast(zc);
                creg[mt][r] = cn;
                union { f16 f; unsigned short u; } cvt;
                cvt.f = (f16)(og * tanh_fast(cn));
                unsigned short* hp = (unsigned short*)halo
                    + ((size_t)((t + 1) * BB + bb) * (HH * WW) + gy * WW + gx) * FF + fch;
                __hip_atomic_store(hp, cvt.u, __ATOMIC_RELAXED, __HIP_MEMORY_SCOPE_AGENT);
            }
        }
        __syncthreads();  // per-wave vmcnt(0) => all h stores at coherent point
        if (tid == 0)
            __hip_atomic_store(&flags[bid], (unsigned)(t + 1), __ATOMIC_RELAXED,
                               __HIP_MEMORY_SCOPE_AGENT);
    }

    // ---- final pool: h[16] from global -> out slot 15 (needs all 4 quarters of own tile) ----
    if (tid < 4) {
        while (__hip_atomic_load(&flags[(tl << 2) | tid], __ATOMIC_RELAXED,
                                 __HIP_MEMORY_SCOPE_AGENT) < (unsigned)TT)
            __builtin_amdgcn_s_sleep(2);
    }
    __syncthreads();
    {
        int a_ = tid >> 6, b_ = (tid >> 3) & 7, ch = (tid & 7) << 3;
        float o8[8];
#pragma unroll
        for (int j = 0; j < 8; j++) o8[j] = -1e30f;
#pragma unroll
        for (int dy2 = 0; dy2 < 2; dy2++)
#pragma unroll
            for (int dx2 = 0; dx2 < 2; dx2++) {
                int gy = tY * 16 + 2 * a_ + dy2, gx = tX * 16 + 2 * b_ + dx2;
                const ull* src = (const ull*)(halo
                    + ((size_t)(TT * BB + bb) * (HH * WW) + gy * WW + gx) * FF + ch);
                ull v0 = __hip_atomic_load(src, __ATOMIC_RELAXED, __HIP_MEMORY_SCOPE_AGENT);
                ull v1 = __hip_atomic_load(src + 1, __ATOMIC_RELAXED, __HIP_MEMORY_SCOPE_AGENT);
                f16 tmp[8];
                *(ull*)&tmp[0] = v0; *(ull*)&tmp[4] = v1;
#pragma unroll
                for (int j = 0; j < 8; j++) o8[j] = fmaxf(o8[j], (float)tmp[j]);
            }
        size_t ofs = ((((size_t)bb * TT + 15) * 32 + tY * 8 + a_) * 32 + (tX * 8 + b_)) * 64 + ch;
        *(float4*)(out + ofs) = *(float4*)&o8[0];
        *(float4*)(out + ofs + 4) = *(float4*)&o8[4];
    }
}

// ================= Fallback path (round-4 proven multi-kernel, uses wcatB) =================
__global__ void ln_kernel(const float* __restrict__ x,
                          const float* __restrict__ gamma,
                          const float* __restrict__ beta,
                          f16* __restrict__ xn) {
    __shared__ float sg[CC], sb[CC];
    if (threadIdx.x < CC) sg[threadIdx.x] = gamma[threadIdx.x];
    else if (threadIdx.x < 2 * CC) sb[threadIdx.x - CC] = beta[threadIdx.x - CC];
    __syncthreads();
    int q = blockIdx.x * 256 + threadIdx.x;
    const float* xp = x + (size_t)q * CC;
    float v[CC];
    float s = 0.f, s2 = 0.f;
#pragma unroll
    for (int c = 0; c < CC; c += 4) {
        float4 t4 = *(const float4*)(xp + c);
        v[c] = t4.x; v[c + 1] = t4.y; v[c + 2] = t4.z; v[c + 3] = t4.w;
        s += t4.x + t4.y + t4.z + t4.w;
        s2 += t4.x * t4.x + t4.y * t4.y + t4.z * t4.z + t4.w * t4.w;
    }
    float mu = s * (1.f / CC);
    float var = s2 * (1.f / CC) - mu * mu;
    float rs = rsqrtf(var + 1e-3f);
    f16 o[CC];
#pragma unroll
    for (int c = 0; c < CC; c++)
        o[c] = (f16)((v[c] - mu) * rs * sg[c] + sb[c]);
    f16x8* d = (f16x8*)(xn + (size_t)q * CC);
#pragma unroll
    for (int c = 0; c < 4; c++) d[c] = *(f16x8*)&o[c * 8];
}

__global__ __launch_bounds__(256, 2)
void step_kernel(const f16* __restrict__ xn, const f16* __restrict__ wcat,
                 const float* __restrict__ bs,
                 float* __restrict__ cst, f16* __restrict__ hs, int t) {
    __shared__ __align__(16) f16 xpatch[100 * 72];
    __shared__ __align__(16) f16 hpatch[100 * 72];
    __shared__ __align__(16) f16 wbuf[2 * 12288];

    int tile = blockIdx.x >> 1, nhalf = blockIdx.x & 1;
    int bb = tile >> 6, ty = (tile >> 3) & 7, tx = tile & 7;
    int tid = threadIdx.x;
    int lane = tid & 63, w = tid >> 6;
    int wm = w >> 1, wn = w & 1;
    int quad = lane >> 4, noff = lane & 15;

    const char* gw[6];
#pragma unroll
    for (int i = 0; i < 6; i++) {
        int g = w * 6 + i;
        int hb = g & 1;
        int gate = (((hb << 1) + (lane >> 5)) << 6) + (nhalf << 5) + (lane & 31);
        gw[i] = (const char*)wcat + ((size_t)(g >> 1) * 256 + gate) * 16;
    }
#pragma unroll
    for (int i = 0; i < 6; i++) {
        int g = w * 6 + i;
        async_copy16(gw[i], &wbuf[(g >> 1) * 1024 + (g & 1) * 512]);
    }

    const f16* xslice = xn + (size_t)(bb * TT + t) * (HH * WW) * CC;
    const f16* hprev = hs + (size_t)t * (BB * HH * WW * FF);
    f16* hnew = hs + (size_t)(t + 1) * (BB * HH * WW * FF);

    if (tid < 200) {
        int pix = tid >> 1, part = tid & 1;
        int py = pix / 10, px = pix % 10;
        int y = ty * 8 - 1 + py, x = tx * 8 - 1 + px;
        bool in = (y >= 0 && y < HH && x >= 0 && x < WW);
        f16x8 z = {0, 0, 0, 0, 0, 0, 0, 0};
        {
            f16x8* d = (f16x8*)&xpatch[pix * 72 + part * 16];
            if (in) {
                const f16x8* s = (const f16x8*)(xslice + ((size_t)y * WW + x) * CC + part * 16);
                d[0] = s[0]; d[1] = s[1];
            } else { d[0] = z; d[1] = z; }
        }
        {
            f16x8* d = (f16x8*)&hpatch[pix * 72 + part * 32];
            if (in) {
                const f16x8* s = (const f16x8*)(hprev + ((size_t)(bb * HH + y) * WW + x) * FF + part * 32);
                d[0] = s[0]; d[1] = s[1]; d[2] = s[2]; d[3] = s[3];
            } else { d[0] = z; d[1] = z; d[2] = z; d[3] = z; }
        }
    }

    int fch = (nhalf << 5) + (wn << 4) + noff;
    float b_i = bs[fch], b_f = bs[64 + fch], b_c = bs[128 + fch], b_o = bs[192 + fch];

    f32x4 acc[2][4];
#pragma unroll
    for (int i = 0; i < 2; i++)
#pragma unroll
        for (int j = 0; j < 4; j++) acc[i][j] = (f32x4){0.f, 0.f, 0.f, 0.f};

#pragma unroll
    for (int p = 0; p < 9; ++p) {
        __syncthreads();
        if (p < 8) {
#pragma unroll
            for (int i = 0; i < 6; i++) {
                int g = w * 6 + i;
                async_copy16(gw[i] + (size_t)(p + 1) * 49152,
                             &wbuf[((p + 1) & 1) * 12288 + (g >> 1) * 1024 + (g & 1) * 512]);
            }
        }
        const f16* wb = &wbuf[(p & 1) * 12288];
#pragma unroll
        for (int cw = 0; cw < 3; ++cw) {
            int c = p * 3 + cw;
            bool isx = c < 9;
            int hc = c - 9;
            int tap = isx ? c : (hc >> 1);
            int coff = isx ? 0 : ((hc & 1) << 5);
            const f16* ap = isx ? xpatch : hpatch;
            int dy = tap / 3, dx = tap % 3;
            f16x8 a[2];
#pragma unroll
            for (int mt = 0; mt < 2; mt++) {
                int m = (wm << 5) + (mt << 4) + noff;
                int pp = ((m >> 3) + dy) * 10 + (m & 7) + dx;
                a[mt] = *(const f16x8*)&ap[pp * 72 + coff + (quad << 3)];
            }
#pragma unroll
            for (int cls = 0; cls < 4; cls++) {
                f16x8 bf = *(const f16x8*)&wb[((cw << 2) + quad) * 1024 + (((cls << 5) + (wn << 4) + noff) << 3)];
                acc[0][cls] = __builtin_amdgcn_mfma_f32_16x16x32_f16(a[0], bf, acc[0][cls], 0, 0, 0);
                acc[1][cls] = __builtin_amdgcn_mfma_f32_16x16x32_f16(a[1], bf, acc[1][cls], 0, 0, 0);
            }
        }
    }

#pragma unroll
    for (int mt = 0; mt < 2; mt++) {
#pragma unroll
        for (int r = 0; r < 4; r++) {
            int m = (wm << 5) + (mt << 4) + (quad << 2) + r;
            int y = ty * 8 + (m >> 3), x = tx * 8 + (m & 7);
            size_t p = (size_t)(bb * HH + y) * WW + x;
            float zi = acc[mt][0][r] + b_i;
            float zf = acc[mt][1][r] + b_f;
            float zc = acc[mt][2][r] + b_c;
            float zo = acc[mt][3][r] + b_o;
            float ig = hsig(zi), fg = hsig(zf), og = hsig(zo);
            float cold = cst[p * FF + fch];
            float cn = fg * cold + ig * tanh_fast(zc);
            cst[p * FF + fch] = cn;
            hnew[p * FF + fch] = (f16)(og * tanh_fast(cn));
        }
    }
}

__global__ void pool_kernel(const f16* __restrict__ hs, float* __restrict__ out) {
    int idx = blockIdx.x * 256 + threadIdx.x;
    int f = idx & 63;
    int ox = (idx >> 6) & 31;
    int oy = (idx >> 11) & 31;
    int t = (idx >> 16) & 15;
    int bb = idx >> 20;
    const f16* base = hs + (size_t)(t + 1) * (BB * HH * WW * FF)
                    + ((size_t)(bb * HH + oy * 2) * WW + ox * 2) * FF + f;
    float v0 = (float)base[0];
    float v1 = (float)base[FF];
    float v2 = (float)base[WW * FF];
    float v3 = (float)base[WW * FF + FF];
    out[idx] = fmaxf(fmaxf(v0, v1), fmaxf(v2, v3));
}

extern "C" void kernel_launch(void* const* d_in, const int* in_sizes, int n_in,
                              void* d_out, int out_size, void* d_ws, size_t ws_size,
                              hipStream_t stream) {
    const float* x = (const float*)d_in[0];
    const float* gamma = (const float*)d_in[1];
    const float* beta = (const float*)d_in[2];
    const float* wx = (const float*)d_in[3];
    const float* wh = (const float*)d_in[4];
    const float* bs = (const float*)d_in[5];
    float* out = (float*)d_out;

    // workspace layout (all 16B-aligned; ws is ~256 MB)
    char* ws = (char*)d_ws;
    f16* xn = (f16*)ws;                       // 16,777,216 B (fallback only)
    f16* wcatB = (f16*)(ws + 16777216);       //    442,368 B (fallback layout)
    float* cst = (float*)(ws + 17219584);     //  4,194,304 B (fallback c-state; fused: flags)
    f16* hs = (f16*)(ws + 21413888);          // 35,651,584 B (h history / halo)
    f16* wcatA = (f16*)(ws + 57065472);       //    442,368 B (fused quarter layout)
    unsigned* flags = (unsigned*)cst;         // 256 x 4 B, disjoint usage

    hipMemsetAsync(flags, 0, 256 * 4, stream);
    wprep_kernel<<<864, 256, 0, stream>>>(wx, wh, wcatA, wcatB);

    void* args[8];
    args[0] = (void*)&x;
    args[1] = (void*)&gamma;
    args[2] = (void*)&beta;
    args[3] = (void*)&wcatA;
    args[4] = (void*)&bs;
    args[5] = (void*)&hs;     // h exchange buffer
    args[6] = (void*)&out;
    args[7] = (void*)&flags;
    hipError_t err = hipLaunchCooperativeKernel((const void*)fused_kernel, dim3(256),
                                                dim3(512), args, 0, stream);
    if (err != hipSuccess) {
        (void)hipGetLastError();  // clear error state; take the proven multi-kernel path
        hipMemsetAsync(cst, 0, (size_t)BB * HH * WW * FF * 4, stream);
        hipMemsetAsync(hs, 0, (size_t)BB * HH * WW * FF * 2, stream);
        ln_kernel<<<1024, 256, 0, stream>>>(x, gamma, beta, xn);
        for (int t = 0; t < TT; t++)
            step_kernel<<<512, 256, 0, stream>>>(xn, wcatB, bs, cst, hs, t);
        pool_kernel<<<16384, 256, 0, stream>>>(hs, out);
    }
}